// Round 7
// baseline (176.634 us; speedup 1.0000x reference)
//
#include <hip/hip_runtime.h>
#include <hip/hip_bf16.h>
#include <stdint.h>

// B=1024, D_IN=2048, D_H=4096, D_OUT=2048, D_INT=1024
// L_W = 2^23 for both weight fastfoods; L_b1=4096, L_b2=2048. LL==DD everywhere.

typedef __attribute__((ext_vector_type(8))) short bf16x8;   // 8 bf16 (4 VGPRs)
typedef __attribute__((ext_vector_type(8))) short short8;
typedef __attribute__((ext_vector_type(4))) float f32x4;

__device__ __forceinline__ ushort f2bf(float f) {           // RNE f32->bf16
  union { float f; uint32_t u; } v; v.f = f;
  return (ushort)((v.u + 0x7FFFu + ((v.u >> 16) & 1u)) >> 16);
}
__device__ __forceinline__ float bf2f(ushort u) {
  union { uint32_t u; float f; } v; v.u = (uint32_t)u << 16; return v.f;
}

__device__ __forceinline__ void gload_lds16(const void* g, void* l) {
  __builtin_amdgcn_global_load_lds(
      (const __attribute__((address_space(1))) void*)g,
      (__attribute__((address_space(3))) void*)l, 16, 0, 0);
}

__device__ __forceinline__ void wait_vm16() { asm volatile("s_waitcnt vmcnt(16)" ::: "memory"); }
__device__ __forceinline__ void wait_vm8()  { asm volatile("s_waitcnt vmcnt(8)"  ::: "memory"); }
__device__ __forceinline__ void wait_vm0()  { asm volatile("s_waitcnt vmcnt(0)"  ::: "memory"); }
__device__ __forceinline__ void wait_lgkm0(){ asm volatile("s_waitcnt lgkmcnt(0)" ::: "memory"); }
__device__ __forceinline__ void barrier_raw(){ asm volatile("s_barrier" ::: "memory"); }

template <int NN>
__device__ __forceinline__ void wht_inreg(float* v) {
#pragma unroll
  for (int h = 1; h < NN; h <<= 1)
#pragma unroll
    for (int g = 0; g < NN; g += (h << 1))
#pragma unroll
      for (int k = 0; k < h; ++k) {
        float a = v[g + k], b = v[g + k + h];
        v[g + k] = a + b; v[g + k + h] = a - b;
      }
}

// ---------------- prep: fused  (a) x f32->bf16 cvt [blocks 0..2047]
//                               (b) t = WHT_1024(BB*V) for W1/W2 [2048..2049]
//                               (c) full bias fastfood b1/b2 [2050..2051]
__global__ __launch_bounds__(256) void prep(
    const float4* __restrict__ x4, ushort4* __restrict__ xb4,
    const float* __restrict__ V,
    const float* __restrict__ BBW1, const float* __restrict__ BBW2,
    float* __restrict__ t1, float* __restrict__ t2,
    const float* __restrict__ BBb1, const int* __restrict__ Pib1,
    const float* __restrict__ GGb1, const float* __restrict__ b10,
    const float* __restrict__ BBb2, const int* __restrict__ Pib2,
    const float* __restrict__ GGb2, const float* __restrict__ b20,
    float* __restrict__ ob1, float* __restrict__ ob2) {
  __shared__ float ts[1024];
  __shared__ float zs[4096];
  __shared__ float red[4];
  const int bid = blockIdx.x;
  const int tid = threadIdx.x;

  if (bid < 2048) {                       // role (a): cvt
    int i = bid * 256 + tid;
    float4 v = x4[i];
    ushort4 o;
    o.x = f2bf(v.x); o.y = f2bf(v.y); o.z = f2bf(v.z); o.w = f2bf(v.w);
    xb4[i] = o;
    return;
  }

  if (bid < 2050) {                       // role (b): make_t
    const int which = bid - 2048;
    const float* BB = which ? BBW2 : BBW1;
    float* t = which ? t2 : t1;
    for (int i = tid; i < 1024; i += 256) ts[i] = BB[i] * V[i];
    for (int st = 0; st < 10; ++st) {
      int half = 1 << st;
      __syncthreads();
      for (int j = tid; j < 512; j += 256) {
        int p = ((j >> st) << (st + 1)) | (j & (half - 1));
        float a = ts[p], b = ts[p + half];
        ts[p] = a + b; ts[p + half] = a - b;
      }
    }
    __syncthreads();
    for (int i = tid; i < 1024; i += 256) t[i] = ts[i];
    return;
  }

  // role (c): bias fastfood
  {
    const int which = bid - 2050;
    const int L = which ? 2048 : 4096;
    const float* BB = which ? BBb2 : BBb1;
    const int* Pi = which ? Pib2 : Pib1;
    const float* GG = which ? GGb2 : GGb1;
    const float* b0 = which ? b20 : b10;
    float* ob = which ? ob2 : ob1;

    for (int i = tid; i < 1024; i += 256) ts[i] = BB[i] * V[i];
    for (int st = 0; st < 10; ++st) {
      int half = 1 << st;
      __syncthreads();
      for (int j = tid; j < 512; j += 256) {
        int p = ((j >> st) << (st + 1)) | (j & (half - 1));
        float a = ts[p], b = ts[p + half];
        ts[p] = a + b; ts[p + half] = a - b;
      }
    }
    __syncthreads();
    float gsum = 0.f;
    for (int i = tid; i < L; i += 256) {
      int pi = Pi[i];
      float g = GG[i];
      gsum += g * g;
      zs[i] = ts[pi & 1023] * g;
    }
    for (int o = 32; o > 0; o >>= 1) gsum += __shfl_down(gsum, o);
    if ((tid & 63) == 0) red[tid >> 6] = gsum;
    __syncthreads();
    float ssum = red[0] + red[1] + red[2] + red[3];
    for (int st = 0; (1 << st) < L; ++st) {
      int half = 1 << st;
      __syncthreads();
      for (int j = tid; j < (L >> 1); j += 256) {
        int p = ((j >> st) << (st + 1)) | (j & (half - 1));
        float a = zs[p], b = zs[p + half];
        zs[p] = a + b; zs[p + half] = a - b;
      }
    }
    __syncthreads();
    float scale = rsqrtf((float)L * ssum);
    for (int i = tid; i < L; i += 256) ob[i] = b0[i] + zs[i] * scale;
  }
}

// ---------------- build_z (both weights): z = bf16( t[Pi&1023] * GG ), pure
// streaming gather from a 4 KB LDS table + per-block sum(G^2). No phase
// structure: 4 KB LDS + ~64 VGPR -> 8 blocks/CU, 32 waves/CU. Per q-pass each
// wave reads 2x2 KB contiguous (int4/float4) and writes 1 KB contiguous
// (short8). This is the max-TLP streaming regime.
__global__ __launch_bounds__(256) void build_z(
    const int* __restrict__ Pi1, const float* __restrict__ GG1,
    const int* __restrict__ Pi2, const float* __restrict__ GG2,
    const float* __restrict__ t1, const float* __restrict__ t2,
    ushort* __restrict__ z1, ushort* __restrict__ z2,
    float* __restrict__ partials) {
  __shared__ float ts[1024];
  __shared__ float red[4];
  const int tid = threadIdx.x;
  const int wsel = blockIdx.x >> 10;
  const int blk = blockIdx.x & 1023;
  const int* __restrict__ Pi = wsel ? Pi2 : Pi1;
  const float* __restrict__ GG = wsel ? GG2 : GG1;
  const float* t = wsel ? t2 : t1;
  ushort* __restrict__ z = wsel ? z2 : z1;
  const size_t base = (size_t)blk << 13;

  for (int i = tid; i < 1024; i += 256) ts[i] = t[i];

  // issue all 16 loads up front (independent streams, no barrier in between)
  int4 p4[8]; float4 g4[8];
  const int4* Pi4 = (const int4*)(Pi + base);
  const float4* GG4 = (const float4*)(GG + base);
#pragma unroll
  for (int q = 0; q < 4; ++q) {
    p4[2 * q]     = Pi4[(q << 9) + (tid << 1)];
    p4[2 * q + 1] = Pi4[(q << 9) + (tid << 1) + 1];
    g4[2 * q]     = GG4[(q << 9) + (tid << 1)];
    g4[2 * q + 1] = GG4[(q << 9) + (tid << 1) + 1];
  }
  __syncthreads();                        // ts ready

  float gsum = 0.f;
#pragma unroll
  for (int q = 0; q < 4; ++q) {
    const int4 pa = p4[2 * q], pb = p4[2 * q + 1];
    const float4 ga = g4[2 * q], gb = g4[2 * q + 1];
    gsum += ga.x * ga.x + ga.y * ga.y + ga.z * ga.z + ga.w * ga.w
          + gb.x * gb.x + gb.y * gb.y + gb.z * gb.z + gb.w * gb.w;
    short8 o;
    o[0] = (short)f2bf(ts[pa.x & 1023] * ga.x);
    o[1] = (short)f2bf(ts[pa.y & 1023] * ga.y);
    o[2] = (short)f2bf(ts[pa.z & 1023] * ga.z);
    o[3] = (short)f2bf(ts[pa.w & 1023] * ga.w);
    o[4] = (short)f2bf(ts[pb.x & 1023] * gb.x);
    o[5] = (short)f2bf(ts[pb.y & 1023] * gb.y);
    o[6] = (short)f2bf(ts[pb.z & 1023] * gb.z);
    o[7] = (short)f2bf(ts[pb.w & 1023] * gb.w);
    *(short8*)(z + base + (q << 11) + (tid << 3)) = o;
  }
  for (int o2 = 32; o2 > 0; o2 >>= 1) gsum += __shfl_down(gsum, o2);
  if ((tid & 63) == 0) red[tid >> 6] = gsum;
  __syncthreads();
  if (tid == 0) partials[blockIdx.x] = red[0] + red[1] + red[2] + red[3];
}

// ---------------- wht13 (both weights): WHT_8192 over bits 0..12 of each
// 8192-chunk of z. One coalesced short8 burst in, radix-32(b0-4) in regs,
// f32 LDS skew phys(i)=i+2*(i>>5) (all phases <=2-way), radix-32(b5-9),
// radix-8(b10-12), coalesced short4 stores. 2 barriers, no gather, no Pi/GG
// registers -> 4 blocks/CU, 16 waves.
__global__ __launch_bounds__(256) void wht13(
    const ushort* __restrict__ zz1, const ushort* __restrict__ zz2,
    ushort* __restrict__ inter1, ushort* __restrict__ inter2) {
  __shared__ float zs[8704];              // 8192 + 2*256 skew (f32)
  const int tid = threadIdx.x;
  const int wsel = blockIdx.x >> 10;
  const int blk = blockIdx.x & 1023;
  const ushort* __restrict__ z = wsel ? zz2 : zz1;
  ushort* __restrict__ inter = wsel ? inter2 : inter1;
  const size_t base = (size_t)blk << 13;

  float v[32];
#pragma unroll
  for (int j = 0; j < 4; ++j) {
    short8 d = *(const short8*)(z + base + (tid << 5) + (j << 3));
#pragma unroll
    for (int k = 0; k < 8; ++k) v[(j << 3) + k] = bf2f((ushort)d[k]);
  }
  wht_inreg<32>(v);                       // bits 0-4
  // T1: thread's 32 elems at phys 34*tid + r (contiguous)
#pragma unroll
  for (int j = 0; j < 16; ++j) {
    float2 u; u.x = v[2 * j]; u.y = v[2 * j + 1];
    *(float2*)&zs[34 * tid + 2 * j] = u;
  }
  __syncthreads();

  // pass B: bits 5-9.  i = lo + 32r + 1024hi -> phys = lo + 34r + 1088hi
  {
    const int pb = (tid & 31) + 1088 * (tid >> 5);
#pragma unroll
    for (int r = 0; r < 32; ++r) v[r] = zs[pb + 34 * r];
    wht_inreg<32>(v);
#pragma unroll
    for (int r = 0; r < 32; ++r) zs[pb + 34 * r] = v[r];
  }
  __syncthreads();

  // pass C: bits 10-12.  i = 4s+k+1024r -> phys = 4s + 2*(s>>3) + k + 1088r
  {
    const int pc = 4 * tid + 2 * (tid >> 3);
    float w[4][8];
#pragma unroll
    for (int r = 0; r < 8; ++r) {
      float2 u0 = *(const float2*)&zs[pc + 1088 * r];
      float2 u1 = *(const float2*)&zs[pc + 1088 * r + 2];
      w[0][r] = u0.x; w[1][r] = u0.y; w[2][r] = u1.x; w[3][r] = u1.y;
    }
#pragma unroll
    for (int k = 0; k < 4; ++k) wht_inreg<8>(w[k]);
    ushort* op = inter + base + 4 * tid;
#pragma unroll
    for (int r = 0; r < 8; ++r) {
      short4 o;
      o.x = (short)f2bf(w[0][r]); o.y = (short)f2bf(w[1][r]);
      o.z = (short)f2bf(w[2][r]); o.w = (short)f2bf(w[3][r]);
      *(short4*)&op[r << 10] = o;
    }
  }
}

// ---------------- pass 2 (both weights, merged): WHT_1024 over h-bits (global
// bits 13..22, stride 8192). Block = 32 cols x all 1024 rows. Pass A: thread
// (p=t&15, g=t>>4) owns rows 32g+r, cols {2p,2p+1}; radix-32 in regs; exchange
// through a [1024][34] bf16 LDS tile; pass B: rows g+32r, radix-32 + fused
// epilogue W = W0 + m5*scale -> bf16.
__global__ __launch_bounds__(512) void ff_pass2(
    const ushort* __restrict__ inter1, const ushort* __restrict__ inter2,
    const float* __restrict__ W01, const float* __restrict__ W02,
    const float* __restrict__ partials,
    ushort* __restrict__ W1b, ushort* __restrict__ W2b) {
  __shared__ ushort tile[1024][34];       // 69632 B
  __shared__ float red[8];
  const int tid = threadIdx.x;
  const int wsel = blockIdx.x >> 8;
  const int cb = (blockIdx.x & 255) << 5;
  const ushort* inter = wsel ? inter2 : inter1;
  const float* W0 = wsel ? W02 : W01;
  ushort* Wb = wsel ? W2b : W1b;

  float s = partials[(wsel << 10) + tid] + partials[(wsel << 10) + tid + 512];
  for (int o = 32; o > 0; o >>= 1) s += __shfl_down(s, o);
  if ((tid & 63) == 0) red[tid >> 6] = s;

  const int p = tid & 15;                 // col pair
  const int g = tid >> 4;                 // 0..31
  const ushort* ip = inter + ((size_t)(g << 5) << 13) + cb + (p << 1);
  float va[32], vb[32];
#pragma unroll
  for (int r = 0; r < 32; ++r) {
    ushort2 u = *(const ushort2*)(ip + ((size_t)r << 13));
    va[r] = bf2f(u.x); vb[r] = bf2f(u.y);
  }
  wht_inreg<32>(va);
  wht_inreg<32>(vb);
#pragma unroll
  for (int r = 0; r < 32; ++r) {
    ushort2 u; u.x = f2bf(va[r]); u.y = f2bf(vb[r]);
    *(ushort2*)&tile[(g << 5) + r][p << 1] = u;
  }
  __syncthreads();                        // tile + red visible
  float ssum = 0.f;
#pragma unroll
  for (int k = 0; k < 8; ++k) ssum += red[k];
  const float sc = rsqrtf(8388608.f * ssum);

  float wa[32], wb[32];
#pragma unroll
  for (int r = 0; r < 32; ++r) {
    ushort2 u = *(const ushort2*)&tile[g + (r << 5)][p << 1];
    wa[r] = bf2f(u.x); wb[r] = bf2f(u.y);
  }
  wht_inreg<32>(wa);
  wht_inreg<32>(wb);
#pragma unroll
  for (int r = 0; r < 32; ++r) {
    size_t m = (((size_t)(g + (r << 5))) << 13) + cb + (p << 1);
    float2 w0 = *(const float2*)(W0 + m);
    ushort2 u;
    u.x = f2bf(wa[r] * sc + w0.x);
    u.y = f2bf(wb[r] * sc + w0.y);
    *(ushort2*)(Wb + m) = u;
  }
}

// ---------------- C = A * B^T  (A: MxK bf16 row-major, B: NxK bf16 row-major)
// 128x128 tile, BK=64, 4 waves (2x2), each wave 64x64 = 4x4 frags of 16x16x32.
// 4-buffer LDS pipeline, 3-deep global_load_lds prefetch, counted vmcnt + raw
// s_barrier (one barrier per K-step; never vmcnt(0) in steady state).
// Both-sides XOR swizzle (src col8 ^= row&7 on global addr, same XOR on read).
// EPI==0: C = bf16(relu(acc + bias)) -> Cb ;  EPI==1: f32 partial -> Cf[z]
template <int EPI, int NT>
__global__ __launch_bounds__(256) void gemm_bt(
    const ushort* __restrict__ A, const ushort* __restrict__ B,
    const float* __restrict__ bias, ushort* __restrict__ Cb, float* __restrict__ Cf,
    int M, int N, int K) {
  __shared__ ushort As[4][8192];
  __shared__ ushort Bs[4][8192];
  const int tid = threadIdx.x;
  const int w = tid >> 6, l = tid & 63;
  const int wr = w >> 1, wc = w & 1;
  const int brow = blockIdx.y << 7, bcol = blockIdx.x << 7;
  const int lrow = l >> 3;                       // row within 8-row chunk
  const int csrc = ((l & 7) ^ lrow) << 3;        // swizzled source col (ushort)
  const int l15 = l & 15;
  const int x7 = l15 & 7;
  const int kb = blockIdx.z * (NT << 6);
  f32x4 acc[4][4] = {};

  const ushort* pa = A + (size_t)(brow + (w << 5) + lrow) * K + kb + csrc;
  const ushort* pb = B + (size_t)(bcol + (w << 5) + lrow) * K + kb + csrc;
  const size_t K8 = (size_t)K << 3;

#define STAGE(buf, tt)                                                      \
  {                                                                         \
    const ushort* qa = pa + ((tt) << 6);                                    \
    const ushort* qb = pb + ((tt) << 6);                                    \
    _Pragma("unroll")                                                       \
    for (int i = 0; i < 4; ++i) {                                           \
      gload_lds16(qa + K8 * i, &As[buf][(((w << 2) + i) << 9)]);            \
      gload_lds16(qb + K8 * i, &Bs[buf][(((w << 2) + i) << 9)]);            \
    }                                                                       \
  }

  STAGE(0, 0); STAGE(1, 1); STAGE(2, 2);      // 24 outstanding per wave
  for (int t = 0; t < NT; ++t) {
    if (t < NT - 2) wait_vm16();              // stage t done, t+1/t+2 in flight
    else if (t == NT - 2) wait_vm8();
    else wait_vm0();
    barrier_raw();
    if (t + 3 < NT) STAGE((t + 3) & 3, t + 3);
    const ushort* Acur = As[t & 3];
    const ushort* Bcur = Bs[t & 3];
    bf16x8 af[2][4], bfr[2][4];
#pragma unroll
    for (int kk = 0; kk < 2; ++kk) {
      int c8 = (kk << 2) + (l >> 4);
#pragma unroll
      for (int m = 0; m < 4; ++m)
        af[kk][m] = *(const bf16x8*)&Acur[(((wr << 6) + (m << 4) + l15) << 6) + ((c8 ^ x7) << 3)];
#pragma unroll
      for (int n = 0; n < 4; ++n)
        bfr[kk][n] = *(const bf16x8*)&Bcur[(((wc << 6) + (n << 4) + l15) << 6) + ((c8 ^ x7) << 3)];
    }
    wait_lgkm0();                              // reads complete before next barrier
#pragma unroll
    for (int kk = 0; kk < 2; ++kk)
#pragma unroll
      for (int m = 0; m < 4; ++m)
#pragma unroll
        for (int n = 0; n < 4; ++n)
          acc[m][n] = __builtin_amdgcn_mfma_f32_16x16x32_bf16(af[kk][m], bfr[kk][n], acc[m][n], 0, 0, 0);
  }
#undef STAGE

  if (EPI == 0) {
#pragma unroll
    for (int n = 0; n < 4; ++n) {
      int col = bcol + (wc << 6) + (n << 4) + l15;
      float bv = bias[col];
#pragma unroll
      for (int m = 0; m < 4; ++m) {
        int row0 = brow + (wr << 6) + (m << 4) + ((l >> 4) << 2);
#pragma unroll
        for (int j = 0; j < 4; ++j) {
          float vv = fmaxf(acc[m][n][j] + bv, 0.f);
          Cb[(size_t)(row0 + j) * N + col] = f2bf(vv);
        }
      }
    }
  } else {
    float* outp = Cf + (size_t)blockIdx.z * M * N;
#pragma unroll
    for (int n = 0; n < 4; ++n) {
      int col = bcol + (wc << 6) + (n << 4) + l15;
#pragma unroll
      for (int m = 0; m < 4; ++m) {
        int row0 = brow + (wr << 6) + (m << 4) + ((l >> 4) << 2);
#pragma unroll
        for (int j = 0; j < 4; ++j)
          outp[(size_t)(row0 + j) * N + col] = acc[m][n][j];
      }
    }
  }
}

// ---------------- out = P0 + P1 + b2   (1024x2048 f32, vectorized f4)
__global__ __launch_bounds__(256) void reduce_out(
    const float4* __restrict__ P, const float* __restrict__ b2,
    float4* __restrict__ out) {
  int i = blockIdx.x * 256 + threadIdx.x;         // 524288 f4
  float4 a = P[i], b = P[i + 524288];
  const float4 bb = *(const float4*)(b2 + ((i & 511) << 2));
  float4 o;
  o.x = a.x + b.x + bb.x; o.y = a.y + b.y + bb.y;
  o.z = a.z + b.z + bb.z; o.w = a.w + b.w + bb.w;
  out[i] = o;
}

extern "C" void kernel_launch(void* const* d_in, const int* in_sizes, int n_in,
                              void* d_out, int out_size, void* d_ws, size_t ws_size,
                              hipStream_t stream) {
  const float* x     = (const float*)d_in[0];
  const float* V     = (const float*)d_in[1];
  const float* W1_0  = (const float*)d_in[2];
  const float* b1_0  = (const float*)d_in[3];
  const float* W2_0  = (const float*)d_in[4];
  const float* b2_0  = (const float*)d_in[5];
  const float* BB_W1 = (const float*)d_in[6];
  const int*   Pi_W1 = (const int*)d_in[7];
  const float* GG_W1 = (const float*)d_in[8];
  const float* BB_b1 = (const float*)d_in[9];
  const int*   Pi_b1 = (const int*)d_in[10];
  const float* GG_b1 = (const float*)d_in[11];
  const float* BB_W2 = (const float*)d_in[12];
  const int*   Pi_W2 = (const int*)d_in[13];
  const float* GG_W2 = (const float*)d_in[14];
  const float* BB_b2 = (const float*)d_in[15];
  const int*   Pi_b2 = (const int*)d_in[16];
  const float* GG_b2 = (const float*)d_in[17];
  float* out = (float*)d_out;

  const size_t MB = 1048576ull;
  char* ws = (char*)d_ws;
  // Aliasing (all verified against the dispatch order):
  //   inter1 (16MB bf16) @0   -- aliases P (f32 partials; inter1 dead by gemm2)
  //   inter2 @16MB
  //   z1 @32MB aliases W1b (z1 dead before pass2 writes W1b)
  //   z2 @48MB aliases W2b
  ushort* inter1 = (ushort*)(ws);
  float*  P      = (float*)(ws);
  ushort* inter2 = (ushort*)(ws + 16 * MB);
  ushort* z1     = (ushort*)(ws + 32 * MB);
  ushort* z2     = (ushort*)(ws + 48 * MB);
  ushort* W1b    = (ushort*)(ws + 32 * MB);
  ushort* W2b    = (ushort*)(ws + 48 * MB);
  ushort* xb     = (ushort*)(ws + 64 * MB);
  ushort* hb     = (ushort*)(ws + 68 * MB);
  char*   S      = ws + 76 * MB;
  float*  t1     = (float*)(S);
  float*  t2     = (float*)(S + 4096);
  float*  b1     = (float*)(S + 8192);
  float*  b2     = (float*)(S + 8192 + 16384);
  float*  parts  = (float*)(S + 8192 + 16384 + 8192);   // 2048 floats

  prep<<<2052, 256, 0, stream>>>((const float4*)x, (ushort4*)xb, V,
                                 BB_W1, BB_W2, t1, t2,
                                 BB_b1, Pi_b1, GG_b1, b1_0,
                                 BB_b2, Pi_b2, GG_b2, b2_0, b1, b2);

  build_z<<<2048, 256, 0, stream>>>(Pi_W1, GG_W1, Pi_W2, GG_W2, t1, t2,
                                    z1, z2, parts);
  wht13<<<2048, 256, 0, stream>>>(z1, z2, inter1, inter2);
  ff_pass2<<<512, 512, 0, stream>>>(inter1, inter2, W1_0, W2_0, parts, W1b, W2b);

  // h = relu(x @ W1^T + b1) -> bf16
  gemm_bt<0, 32><<<dim3(32, 8, 1), 256, 0, stream>>>(xb, W1b, b1, hb, nullptr, 1024, 4096, 2048);
  // out partials = h @ W2^T (split-K2), then out = P0+P1+b2
  gemm_bt<1, 32><<<dim3(16, 8, 2), 256, 0, stream>>>(hb, W2b, nullptr, nullptr, P, 1024, 2048, 4096);
  reduce_out<<<2048, 256, 0, stream>>>((const float4*)P, b2, (float4*)out);
}

// Round 8
// 171.460 us; speedup vs baseline: 1.0302x; 1.0302x over previous
//
#include <hip/hip_runtime.h>
#include <hip/hip_bf16.h>
#include <stdint.h>

// B=1024, D_IN=2048, D_H=4096, D_OUT=2048, D_INT=1024
// L_W = 2^23 for both weight fastfoods; L_b1=4096, L_b2=2048. LL==DD everywhere.

typedef __attribute__((ext_vector_type(8))) short bf16x8;   // 8 bf16 (4 VGPRs)
typedef __attribute__((ext_vector_type(8))) short short8;
typedef __attribute__((ext_vector_type(4))) float f32x4;

__device__ __forceinline__ ushort f2bf(float f) {           // RNE f32->bf16
  union { float f; uint32_t u; } v; v.f = f;
  return (ushort)((v.u + 0x7FFFu + ((v.u >> 16) & 1u)) >> 16);
}
__device__ __forceinline__ float bf2f(ushort u) {
  union { uint32_t u; float f; } v; v.u = (uint32_t)u << 16; return v.f;
}

__device__ __forceinline__ void gload_lds16(const void* g, void* l) {
  __builtin_amdgcn_global_load_lds(
      (const __attribute__((address_space(1))) void*)g,
      (__attribute__((address_space(3))) void*)l, 16, 0, 0);
}

__device__ __forceinline__ void wait_vm16() { asm volatile("s_waitcnt vmcnt(16)" ::: "memory"); }
__device__ __forceinline__ void wait_vm8()  { asm volatile("s_waitcnt vmcnt(8)"  ::: "memory"); }
__device__ __forceinline__ void wait_vm0()  { asm volatile("s_waitcnt vmcnt(0)"  ::: "memory"); }
__device__ __forceinline__ void wait_lgkm0(){ asm volatile("s_waitcnt lgkmcnt(0)" ::: "memory"); }
__device__ __forceinline__ void barrier_raw(){ asm volatile("s_barrier" ::: "memory"); }

template <int NN>
__device__ __forceinline__ void wht_inreg(float* v) {
#pragma unroll
  for (int h = 1; h < NN; h <<= 1)
#pragma unroll
    for (int g = 0; g < NN; g += (h << 1))
#pragma unroll
      for (int k = 0; k < h; ++k) {
        float a = v[g + k], b = v[g + k + h];
        v[g + k] = a + b; v[g + k + h] = a - b;
      }
}

// ---------------- prep: fused  (a) x f32->bf16 cvt [blocks 0..2047]
//                               (b) t = WHT_1024(BB*V) for W1/W2 [2048..2049]
//                               (c) full bias fastfood b1/b2 [2050..2051]
__global__ __launch_bounds__(256) void prep(
    const float4* __restrict__ x4, ushort4* __restrict__ xb4,
    const float* __restrict__ V,
    const float* __restrict__ BBW1, const float* __restrict__ BBW2,
    float* __restrict__ t1, float* __restrict__ t2,
    const float* __restrict__ BBb1, const int* __restrict__ Pib1,
    const float* __restrict__ GGb1, const float* __restrict__ b10,
    const float* __restrict__ BBb2, const int* __restrict__ Pib2,
    const float* __restrict__ GGb2, const float* __restrict__ b20,
    float* __restrict__ ob1, float* __restrict__ ob2) {
  __shared__ float ts[1024];
  __shared__ float zs[4096];
  __shared__ float red[4];
  const int bid = blockIdx.x;
  const int tid = threadIdx.x;

  if (bid < 2048) {                       // role (a): cvt
    int i = bid * 256 + tid;
    float4 v = x4[i];
    ushort4 o;
    o.x = f2bf(v.x); o.y = f2bf(v.y); o.z = f2bf(v.z); o.w = f2bf(v.w);
    xb4[i] = o;
    return;
  }

  if (bid < 2050) {                       // role (b): make_t
    const int which = bid - 2048;
    const float* BB = which ? BBW2 : BBW1;
    float* t = which ? t2 : t1;
    for (int i = tid; i < 1024; i += 256) ts[i] = BB[i] * V[i];
    for (int st = 0; st < 10; ++st) {
      int half = 1 << st;
      __syncthreads();
      for (int j = tid; j < 512; j += 256) {
        int p = ((j >> st) << (st + 1)) | (j & (half - 1));
        float a = ts[p], b = ts[p + half];
        ts[p] = a + b; ts[p + half] = a - b;
      }
    }
    __syncthreads();
    for (int i = tid; i < 1024; i += 256) t[i] = ts[i];
    return;
  }

  // role (c): bias fastfood
  {
    const int which = bid - 2050;
    const int L = which ? 2048 : 4096;
    const float* BB = which ? BBb2 : BBb1;
    const int* Pi = which ? Pib2 : Pib1;
    const float* GG = which ? GGb2 : GGb1;
    const float* b0 = which ? b20 : b10;
    float* ob = which ? ob2 : ob1;

    for (int i = tid; i < 1024; i += 256) ts[i] = BB[i] * V[i];
    for (int st = 0; st < 10; ++st) {
      int half = 1 << st;
      __syncthreads();
      for (int j = tid; j < 512; j += 256) {
        int p = ((j >> st) << (st + 1)) | (j & (half - 1));
        float a = ts[p], b = ts[p + half];
        ts[p] = a + b; ts[p + half] = a - b;
      }
    }
    __syncthreads();
    float gsum = 0.f;
    for (int i = tid; i < L; i += 256) {
      int pi = Pi[i];
      float g = GG[i];
      gsum += g * g;
      zs[i] = ts[pi & 1023] * g;
    }
    for (int o = 32; o > 0; o >>= 1) gsum += __shfl_down(gsum, o);
    if ((tid & 63) == 0) red[tid >> 6] = gsum;
    __syncthreads();
    float ssum = red[0] + red[1] + red[2] + red[3];
    for (int st = 0; (1 << st) < L; ++st) {
      int half = 1 << st;
      __syncthreads();
      for (int j = tid; j < (L >> 1); j += 256) {
        int p = ((j >> st) << (st + 1)) | (j & (half - 1));
        float a = zs[p], b = zs[p + half];
        zs[p] = a + b; zs[p + half] = a - b;
      }
    }
    __syncthreads();
    float scale = rsqrtf((float)L * ssum);
    for (int i = tid; i < L; i += 256) ob[i] = b0[i] + zs[i] * scale;
  }
}

// ---------------- pass 1 (both weights): z = t[Pi&1023]*GG, WHT_8192 on
// contiguous 8192-chunks (bits 0..12) via radix 32(b3-7)/32(b8-12)/8(b0-2)
// register passes; skewed f32 LDS slot = i + (i>>5) keeps all phases <=2-way.
// int4/float4 gathers, short8 coalesced bf16 stores, per-chunk GG^2 partial.
// [Proven structure: r3 = 56.9 us. r4-r7 variants all >= this.]
__global__ __launch_bounds__(256) void ff_pass1(
    const int* __restrict__ Pi1, const float* __restrict__ GG1,
    const int* __restrict__ Pi2, const float* __restrict__ GG2,
    const float* __restrict__ t1, const float* __restrict__ t2,
    ushort* __restrict__ inter1, ushort* __restrict__ inter2,
    float* __restrict__ partials) {
  __shared__ float ts[1024];
  __shared__ float zs[8448];        // 8192 + skew
  __shared__ float red[4];
  int tid = threadIdx.x;
  int wsel = blockIdx.x >> 10;
  int blk = blockIdx.x & 1023;
  const int* Pi = wsel ? Pi2 : Pi1;
  const float* GG = wsel ? GG2 : GG1;
  const float* t = wsel ? t2 : t1;
  ushort* inter = wsel ? inter2 : inter1;
  size_t base = (size_t)blk * 8192;

  for (int i = tid; i < 1024; i += 256) ts[i] = t[i];
  __syncthreads();

  const int4* Pi4 = (const int4*)(Pi + base);
  const float4* GG4 = (const float4*)(GG + base);
  float gsum = 0.f;
#pragma unroll
  for (int q = 0; q < 8; ++q) {
    int u = (q << 8) + tid;          // 0..2047
    int4 p4 = Pi4[u];
    float4 g4 = GG4[u];
    gsum += g4.x * g4.x + g4.y * g4.y + g4.z * g4.z + g4.w * g4.w;
    int i0 = u << 2;
    float4 z;
    z.x = ts[p4.x & 1023] * g4.x;
    z.y = ts[p4.y & 1023] * g4.y;
    z.z = ts[p4.z & 1023] * g4.z;
    z.w = ts[p4.w & 1023] * g4.w;
    *(float4*)&zs[i0 + (i0 >> 5)] = z;
  }
  for (int o = 32; o > 0; o >>= 1) gsum += __shfl_down(gsum, o);
  if ((tid & 63) == 0) red[tid >> 6] = gsum;
  __syncthreads();
  if (tid == 0) partials[blockIdx.x] = red[0] + red[1] + red[2] + red[3];

  float v[32];
  // pass A: bits 3-7
  {
    int o = (tid & 7) | ((tid >> 3) << 8);
#pragma unroll
    for (int r = 0; r < 32; ++r) { int i = o + (r << 3); v[r] = zs[i + (i >> 5)]; }
    wht_inreg<32>(v);
#pragma unroll
    for (int r = 0; r < 32; ++r) { int i = o + (r << 3); zs[i + (i >> 5)] = v[r]; }
  }
  __syncthreads();
  // pass B: bits 8-12
  {
#pragma unroll
    for (int r = 0; r < 32; ++r) { int i = tid | (r << 8); v[r] = zs[i + (i >> 5)]; }
    wht_inreg<32>(v);
#pragma unroll
    for (int r = 0; r < 32; ++r) { int i = tid | (r << 8); zs[i + (i >> 5)] = v[r]; }
  }
  __syncthreads();
  // pass C: bits 0-2 (4 runs of 8) + coalesced short8 stores
  {
    int tp = ((tid & 63) << 3) | ((tid >> 6) << 11);
#pragma unroll
    for (int j = 0; j < 4; ++j)
#pragma unroll
      for (int k = 0; k < 8; ++k) { int i = tp + (j << 9) + k; v[(j << 3) + k] = zs[i + (i >> 5)]; }
#pragma unroll
    for (int j = 0; j < 4; ++j) wht_inreg<8>(v + (j << 3));
#pragma unroll
    for (int j = 0; j < 4; ++j) {
      short8 s;
#pragma unroll
      for (int k = 0; k < 8; ++k) s[k] = (short)f2bf(v[(j << 3) + k]);
      *(short8*)(inter + base + tp + (j << 9)) = s;
    }
  }
}

// ---------------- pass 2 (both weights): WHT_1024 over h (global bits 13..22,
// stride 8192) on a [1024 rows x 64 cols] bf16 LDS tile (128 KB, 1 block/CU,
// 256 blocks = one full-GPU round). XOR-swizzled 16B granules: phys byte =
// row*128 + ((j ^ (row&7))<<4) (+4B sub-offset). Phase1/epilogue b128 ops run
// at the 8-slot minimum; both column passes are 2-way (free). All global I/O
// is full-128B-line: short8 inter loads, float4 W0 reads, short8 Wb stores.
__global__ __launch_bounds__(512) void ff_pass2(
    const ushort* __restrict__ inter1, const ushort* __restrict__ inter2,
    const float* __restrict__ W01, const float* __restrict__ W02,
    const float* __restrict__ partials,
    ushort* __restrict__ W1b, ushort* __restrict__ W2b) {
  __shared__ ushort tile[65536];          // 128 KB
  __shared__ float red[8];
  const int tid = threadIdx.x;
  const int wsel = blockIdx.x >> 7;
  const int cb = (blockIdx.x & 127) << 6;
  const ushort* __restrict__ inter = wsel ? inter2 : inter1;
  const float* __restrict__ W0 = wsel ? W02 : W01;
  ushort* __restrict__ Wb = wsel ? W2b : W1b;
  char* tb = (char*)tile;

  float s = partials[(wsel << 10) + tid] + partials[(wsel << 10) + tid + 512];
  for (int o = 32; o > 0; o >>= 1) s += __shfl_down(s, o);
  if ((tid & 63) == 0) red[tid >> 6] = s;

  // phase 1: coalesced row loads (128 B/lane/row), swizzled LDS stores
#pragma unroll
  for (int h = 0; h < 2; ++h) {
    int r = tid + (h << 9);
    const ushort* gp = inter + ((size_t)r << 13) + cb;
#pragma unroll
    for (int j = 0; j < 8; ++j) {
      short8 d = *(const short8*)(gp + (j << 3));
      *(short8*)(tb + (r << 7) + ((j ^ (r & 7)) << 4)) = d;
    }
  }
  __syncthreads();
  float ssum = 0.f;
#pragma unroll
  for (int k = 0; k < 8; ++k) ssum += red[k];
  const float sc = rsqrtf(8388608.f * ssum);

  const int p = tid & 31;                 // col pair 2p
  const int j0 = p >> 2;                  // granule index
  const int ob = (p & 3) << 2;            // byte offset within granule
  // pass A: rows 32*ge + r  (two sweeps: ge = tid>>5 and +16)
#pragma unroll
  for (int swp = 0; swp < 2; ++swp) {
    const int ge = (tid >> 5) + (swp << 4);
    float va[32], vb[32];
#pragma unroll
    for (int r = 0; r < 32; ++r) {
      int row = (ge << 5) + r;
      ushort2 u = *(const ushort2*)(tb + (row << 7) + ((j0 ^ (row & 7)) << 4) + ob);
      va[r] = bf2f(u.x); vb[r] = bf2f(u.y);
    }
    wht_inreg<32>(va); wht_inreg<32>(vb);
#pragma unroll
    for (int r = 0; r < 32; ++r) {
      int row = (ge << 5) + r;
      ushort2 u; u.x = f2bf(va[r]); u.y = f2bf(vb[r]);
      *(ushort2*)(tb + (row << 7) + ((j0 ^ (row & 7)) << 4) + ob) = u;
    }
  }
  __syncthreads();
  // pass B: rows ge + 32*r
#pragma unroll
  for (int swp = 0; swp < 2; ++swp) {
    const int ge = (tid >> 5) + (swp << 4);
    float va[32], vb[32];
#pragma unroll
    for (int r = 0; r < 32; ++r) {
      int row = ge + (r << 5);
      ushort2 u = *(const ushort2*)(tb + (row << 7) + ((j0 ^ (row & 7)) << 4) + ob);
      va[r] = bf2f(u.x); vb[r] = bf2f(u.y);
    }
    wht_inreg<32>(va); wht_inreg<32>(vb);
#pragma unroll
    for (int r = 0; r < 32; ++r) {
      int row = ge + (r << 5);
      ushort2 u; u.x = f2bf(va[r]); u.y = f2bf(vb[r]);
      *(ushort2*)(tb + (row << 7) + ((j0 ^ (row & 7)) << 4) + ob) = u;
    }
  }
  __syncthreads();
  // epilogue: coalesced rows; W = W0 + m5*sc -> bf16 (full-line r/w)
#pragma unroll
  for (int h = 0; h < 2; ++h) {
    int r = tid + (h << 9);
    size_t gb = ((size_t)r << 13) + cb;
#pragma unroll
    for (int j = 0; j < 8; ++j) {
      short8 d = *(const short8*)(tb + (r << 7) + ((j ^ (r & 7)) << 4));
      float4 w0a = *(const float4*)(W0 + gb + (j << 3));
      float4 w0b = *(const float4*)(W0 + gb + (j << 3) + 4);
      short8 o;
      o[0] = (short)f2bf(bf2f((ushort)d[0]) * sc + w0a.x);
      o[1] = (short)f2bf(bf2f((ushort)d[1]) * sc + w0a.y);
      o[2] = (short)f2bf(bf2f((ushort)d[2]) * sc + w0a.z);
      o[3] = (short)f2bf(bf2f((ushort)d[3]) * sc + w0a.w);
      o[4] = (short)f2bf(bf2f((ushort)d[4]) * sc + w0b.x);
      o[5] = (short)f2bf(bf2f((ushort)d[5]) * sc + w0b.y);
      o[6] = (short)f2bf(bf2f((ushort)d[6]) * sc + w0b.z);
      o[7] = (short)f2bf(bf2f((ushort)d[7]) * sc + w0b.w);
      *(short8*)(Wb + gb + (j << 3)) = o;
    }
  }
}

// ---------------- C = A * B^T  (A: MxK bf16 row-major, B: NxK bf16 row-major)
// 128x128 tile, BK=64, 4 waves (2x2), each wave 64x64 = 4x4 frags of 16x16x32.
// 4-buffer LDS pipeline, 3-deep global_load_lds prefetch, counted vmcnt + raw
// s_barrier (one barrier per K-step; never vmcnt(0) in steady state).
// Both-sides XOR swizzle (src col8 ^= row&7 on global addr, same XOR on read).
// EPI==0: C = bf16(relu(acc + bias)) -> Cb ;  EPI==1: f32 partial -> Cf[z]
template <int EPI, int NT>
__global__ __launch_bounds__(256) void gemm_bt(
    const ushort* __restrict__ A, const ushort* __restrict__ B,
    const float* __restrict__ bias, ushort* __restrict__ Cb, float* __restrict__ Cf,
    int M, int N, int K) {
  __shared__ ushort As[4][8192];
  __shared__ ushort Bs[4][8192];
  const int tid = threadIdx.x;
  const int w = tid >> 6, l = tid & 63;
  const int wr = w >> 1, wc = w & 1;
  const int brow = blockIdx.y << 7, bcol = blockIdx.x << 7;
  const int lrow = l >> 3;                       // row within 8-row chunk
  const int csrc = ((l & 7) ^ lrow) << 3;        // swizzled source col (ushort)
  const int l15 = l & 15;
  const int x7 = l15 & 7;
  const int kb = blockIdx.z * (NT << 6);
  f32x4 acc[4][4] = {};

  const ushort* pa = A + (size_t)(brow + (w << 5) + lrow) * K + kb + csrc;
  const ushort* pb = B + (size_t)(bcol + (w << 5) + lrow) * K + kb + csrc;
  const size_t K8 = (size_t)K << 3;

#define STAGE(buf, tt)                                                      \
  {                                                                         \
    const ushort* qa = pa + ((tt) << 6);                                    \
    const ushort* qb = pb + ((tt) << 6);                                    \
    _Pragma("unroll")                                                       \
    for (int i = 0; i < 4; ++i) {                                           \
      gload_lds16(qa + K8 * i, &As[buf][(((w << 2) + i) << 9)]);            \
      gload_lds16(qb + K8 * i, &Bs[buf][(((w << 2) + i) << 9)]);            \
    }                                                                       \
  }

  STAGE(0, 0); STAGE(1, 1); STAGE(2, 2);      // 24 outstanding per wave
  for (int t = 0; t < NT; ++t) {
    if (t < NT - 2) wait_vm16();              // stage t done, t+1/t+2 in flight
    else if (t == NT - 2) wait_vm8();
    else wait_vm0();
    barrier_raw();
    if (t + 3 < NT) STAGE((t + 3) & 3, t + 3);
    const ushort* Acur = As[t & 3];
    const ushort* Bcur = Bs[t & 3];
    bf16x8 af[2][4], bfr[2][4];
#pragma unroll
    for (int kk = 0; kk < 2; ++kk) {
      int c8 = (kk << 2) + (l >> 4);
#pragma unroll
      for (int m = 0; m < 4; ++m)
        af[kk][m] = *(const bf16x8*)&Acur[(((wr << 6) + (m << 4) + l15) << 6) + ((c8 ^ x7) << 3)];
#pragma unroll
      for (int n = 0; n < 4; ++n)
        bfr[kk][n] = *(const bf16x8*)&Bcur[(((wc << 6) + (n << 4) + l15) << 6) + ((c8 ^ x7) << 3)];
    }
    wait_lgkm0();                              // reads complete before next barrier
#pragma unroll
    for (int kk = 0; kk < 2; ++kk)
#pragma unroll
      for (int m = 0; m < 4; ++m)
#pragma unroll
        for (int n = 0; n < 4; ++n)
          acc[m][n] = __builtin_amdgcn_mfma_f32_16x16x32_bf16(af[kk][m], bfr[kk][n], acc[m][n], 0, 0, 0);
  }
#undef STAGE

  if (EPI == 0) {
#pragma unroll
    for (int n = 0; n < 4; ++n) {
      int col = bcol + (wc << 6) + (n << 4) + l15;
      float bv = bias[col];
#pragma unroll
      for (int m = 0; m < 4; ++m) {
        int row0 = brow + (wr << 6) + (m << 4) + ((l >> 4) << 2);
#pragma unroll
        for (int j = 0; j < 4; ++j) {
          float vv = fmaxf(acc[m][n][j] + bv, 0.f);
          Cb[(size_t)(row0 + j) * N + col] = f2bf(vv);
        }
      }
    }
  } else {
    float* outp = Cf + (size_t)blockIdx.z * M * N;
#pragma unroll
    for (int n = 0; n < 4; ++n) {
      int col = bcol + (wc << 6) + (n << 4) + l15;
#pragma unroll
      for (int m = 0; m < 4; ++m) {
        int row0 = brow + (wr << 6) + (m << 4) + ((l >> 4) << 2);
#pragma unroll
        for (int j = 0; j < 4; ++j)
          outp[(size_t)(row0 + j) * N + col] = acc[m][n][j];
      }
    }
  }
}

// ---------------- out = P0 + P1 + b2   (1024x2048 f32, vectorized f4)
__global__ __launch_bounds__(256) void reduce_out(
    const float4* __restrict__ P, const float* __restrict__ b2,
    float4* __restrict__ out) {
  int i = blockIdx.x * 256 + threadIdx.x;         // 524288 f4
  float4 a = P[i], b = P[i + 524288];
  const float4 bb = *(const float4*)(b2 + ((i & 511) << 2));
  float4 o;
  o.x = a.x + b.x + bb.x; o.y = a.y + b.y + bb.y;
  o.z = a.z + b.z + bb.z; o.w = a.w + b.w + bb.w;
  out[i] = o;
}

extern "C" void kernel_launch(void* const* d_in, const int* in_sizes, int n_in,
                              void* d_out, int out_size, void* d_ws, size_t ws_size,
                              hipStream_t stream) {
  const float* x     = (const float*)d_in[0];
  const float* V     = (const float*)d_in[1];
  const float* W1_0  = (const float*)d_in[2];
  const float* b1_0  = (const float*)d_in[3];
  const float* W2_0  = (const float*)d_in[4];
  const float* b2_0  = (const float*)d_in[5];
  const float* BB_W1 = (const float*)d_in[6];
  const int*   Pi_W1 = (const int*)d_in[7];
  const float* GG_W1 = (const float*)d_in[8];
  const float* BB_b1 = (const float*)d_in[9];
  const int*   Pi_b1 = (const int*)d_in[10];
  const float* GG_b1 = (const float*)d_in[11];
  const float* BB_W2 = (const float*)d_in[12];
  const int*   Pi_W2 = (const int*)d_in[13];
  const float* GG_W2 = (const float*)d_in[14];
  const float* BB_b2 = (const float*)d_in[15];
  const int*   Pi_b2 = (const int*)d_in[16];
  const float* GG_b2 = (const float*)d_in[17];
  float* out = (float*)d_out;

  const size_t MB = 1048576ull;
  char* ws = (char*)d_ws;
  // inter1 (bf16, 16MB) aliases P (f32 partials, 16MB): inter1 dead before gemm2.
  ushort* inter1 = (ushort*)(ws);
  float*  P      = (float*)(ws);
  ushort* inter2 = (ushort*)(ws + 16 * MB);
  ushort* W1b    = (ushort*)(ws + 32 * MB);
  ushort* W2b    = (ushort*)(ws + 48 * MB);
  ushort* xb     = (ushort*)(ws + 64 * MB);
  ushort* hb     = (ushort*)(ws + 68 * MB);
  char*   S      = ws + 76 * MB;
  float*  t1     = (float*)(S);
  float*  t2     = (float*)(S + 4096);
  float*  b1     = (float*)(S + 8192);
  float*  b2     = (float*)(S + 8192 + 16384);
  float*  parts  = (float*)(S + 8192 + 16384 + 8192);   // 2048 floats

  prep<<<2052, 256, 0, stream>>>((const float4*)x, (ushort4*)xb, V,
                                 BB_W1, BB_W2, t1, t2,
                                 BB_b1, Pi_b1, GG_b1, b1_0,
                                 BB_b2, Pi_b2, GG_b2, b2_0, b1, b2);

  ff_pass1<<<2048, 256, 0, stream>>>(Pi_W1, GG_W1, Pi_W2, GG_W2, t1, t2,
                                     inter1, inter2, parts);
  ff_pass2<<<256, 512, 0, stream>>>(inter1, inter2, W1_0, W2_0, parts, W1b, W2b);

  // h = relu(x @ W1^T + b1) -> bf16
  gemm_bt<0, 32><<<dim3(32, 8, 1), 256, 0, stream>>>(xb, W1b, b1, hb, nullptr, 1024, 4096, 2048);
  // out partials = h @ W2^T (split-K2), then out = P0+P1+b2
  gemm_bt<1, 32><<<dim3(16, 8, 2), 256, 0, stream>>>(hb, W2b, nullptr, nullptr, P, 1024, 2048, 4096);
  reduce_out<<<2048, 256, 0, stream>>>((const float4*)P, b2, (float4*)out);
}